// Round 7
// baseline (220.910 us; speedup 1.0000x reference)
//
#include <hip/hip_runtime.h>
#include <hip/hip_bf16.h>

#define N_ROWS 8192
#define D_DIM  4096
#define E_DIM  64
#define BR     32                 // rows per block
#define BK     256                // fp32 K elems per staged chunk
#define NCH    (D_DIM / BK)       // 16 chunks
#define NSTEP  (BK / 32)          // 8 K32-steps per chunk

typedef __attribute__((ext_vector_type(8))) short  short8;
typedef __attribute__((ext_vector_type(4))) float  floatx4;
typedef __attribute__((ext_vector_type(8))) float  float8;

// Split an fp32 vector into hi (RNE bf16) + lo (chopped bf16 of remainder).
// Bitwise-identical to the verified kernel -> identical numerics.
__device__ inline void cvt_split(const float8& f, short8& hi, short8& lo) {
#pragma unroll
  for (int j = 0; j < 8; ++j) {
    float x = f[j];
    unsigned int u  = __builtin_bit_cast(unsigned int, x);
    unsigned int rh = (u + 0x7FFFu + ((u >> 16) & 1u)) >> 16;  // RNE to bf16
    hi[j] = (short)rh;
    float hf = __builtin_bit_cast(float, rh << 16);
    float lf = x - hf;
    unsigned int ul = __builtin_bit_cast(unsigned int, lf);
    lo[j] = (short)(ul >> 16);                                  // chop
  }
}

// ---------------------------------------------------------------------------
// Prep kernel: convert W fp32 [64][4096] -> d_ws split-bf16 in FRAGMENT order.
// For K32-step s (0..127), expert tile e (0..3), plane p (hi/lo), lane l:
//   16B fragment = W rows e*16+(l&15), k = s*32+(l>>4)*8 .. +7
//   stored at ws + (s*8 + e*2 + p)*1024 + l*16          (total 1 MB)
// ---------------------------------------------------------------------------
__global__ __launch_bounds__(512) void prep_w(const void* __restrict__ xv,
                                              const void* __restrict__ wv,
                                              void* __restrict__ ws) {
  __shared__ int sflag;
  const int tid = threadIdx.x;
  if (tid < 64) {   // dtype probe (skip conversion if inputs are bf16)
    unsigned int v = ((const unsigned int*)xv)[(size_t)tid * 997];
    unsigned int e = (v >> 7) & 0xFFu;
    unsigned long long m = __ballot(e >= 100u && e <= 140u);
    if (tid == 0) sflag = (__popcll(m) > 32) ? 1 : 0;
  }
  __syncthreads();
  if (sflag) return;
  const int t    = blockIdx.x * 512 + tid;   // 64 blocks x 512 = 32768
  const int lane = t & 63;
  const int idx  = t >> 6;                    // s*4 + e
  const int s    = idx >> 2;
  const int e    = idx & 3;
  const int row  = e * 16 + (lane & 15);
  const int col  = s * 32 + (lane >> 4) * 8;
  float8 f = *(const float8*)((const float*)wv + (size_t)row * D_DIM + col);
  short8 h, l;
  cvt_split(f, h, l);
  char* d = (char*)ws + (size_t)idx * 2048 + lane * 16;
  *(short8*)d          = h;
  *(short8*)(d + 1024) = l;
}

// ---------------------------------------------------------------------------
// Main fused router: 256 blocks x 256 threads. Block = 32 rows, all 64
// experts. 4 waves: wave w -> expert tile w, BOTH 16-row subtiles.
//
// Round-7 theory: B-fragment re-read BANDWIDTH (1 MB per block) was the
// floor. Fixes:
//  * 32 rows/block with intra-wave B reuse (each B frag feeds 2 row
//    subtiles, 6 MFMAs/step) -> grid-wide B traffic 512 MB -> 256 MB.
//  * main-loop barrier = inline "s_waitcnt lgkmcnt(0); s_barrier" —
//    LDS-visibility only. __syncthreads' vmcnt(0) drain was landing every
//    B/x prefetch at every chunk boundary; now they fly across barriers,
//    waited only at their consumers (compiler data-dep waitcnt).
//  * B frags in NAMED regs (rule #20), prefetched one chunk ahead (as r6).
// x staging: reg-staged split-bf16 LDS, double-buffered, slot^row XOR
// swizzle on write+read ((row+16)&7 == row&7, so one XOR serves both subs).
// ---------------------------------------------------------------------------
__global__ __launch_bounds__(256, 1) void router_kernel(
    const void* __restrict__ xv, const void* __restrict__ wv,
    const void* __restrict__ bv, const void* __restrict__ wsv,
    float* __restrict__ out) {
  __shared__ __align__(16) char sm[2][32768];   // per buffer: xh 16K | xl 16K
  __shared__ float lg[BR][E_DIM + 4];
  __shared__ int   sflag;

  const int tid = threadIdx.x;

  if (tid < 64) {   // dtype probe
    unsigned int v = ((const unsigned int*)xv)[(size_t)tid * 997];
    unsigned int e = (v >> 7) & 0xFFu;
    unsigned long long m = __ballot(e >= 100u && e <= 140u);
    if (tid == 0) sflag = (__popcll(m) > 32) ? 1 : 0;
  }
  __syncthreads();
  const int isbf = sflag;

  const int wave = tid >> 6;            // expert tile 0..3
  const int lane = tid & 63;
  const int lm   = lane & 15;           // A: row-in-subtile  B: expert-in-tile
  const int t4   = lane >> 4;           // k sub-slot within 32-wide K step
  const int r0   = blockIdx.x * BR;

  floatx4 acc0 = {0.f, 0.f, 0.f, 0.f};  // rows 0..15
  floatx4 acc1 = {0.f, 0.f, 0.f, 0.f};  // rows 16..31

  if (!isbf) {
    // staging geometry: thread -> 32 consecutive floats (128B) of one row
    const int srow = tid >> 3;          // 0..31
    const int grp  = tid & 7;           // 32-float col group
    const float* xg = (const float*)xv + (size_t)(r0 + srow) * D_DIM + grp * 32;
    const int ws0 = srow * 512 + (((grp * 4 + 0) ^ (srow & 7)) << 4);
    const int ws1 = srow * 512 + (((grp * 4 + 1) ^ (srow & 7)) << 4);
    const int ws2 = srow * 512 + (((grp * 4 + 2) ^ (srow & 7)) << 4);
    const int ws3 = srow * 512 + (((grp * 4 + 3) ^ (srow & 7)) << 4);
    // B fragment base for this wave's expert tile (+lane*16 per fragment)
    const char* wb = (const char*)wsv + (size_t)wave * 2048 + lane * 16;
    // A read bases: sub0 row = lm, sub1 row = 16+lm; (16+lm)&7 == lm&7
    const int ra  = lm * 512;
    const int axr = lm & 7;

    // named B-fragment registers (NO arrays -> stay in VGPRs)
    short8 bh0, bh1, bh2, bh3, bh4, bh5, bh6, bh7;
    short8 bl0, bl1, bl2, bl3, bl4, bl5, bl6, bl7;

#define LDB(K, BASE)                                                       \
    bh##K = *(const short8*)((BASE) + (size_t)(K) * 8192);                 \
    bl##K = *(const short8*)((BASE) + (size_t)(K) * 8192 + 1024);

#define STAGE(DST, F0, F1, F2, F3)                                         \
    {                                                                      \
      short8 h, l;                                                         \
      cvt_split(F0, h, l); *(short8*)((DST) + ws0) = h;                    \
                           *(short8*)((DST) + 16384 + ws0) = l;            \
      cvt_split(F1, h, l); *(short8*)((DST) + ws1) = h;                    \
                           *(short8*)((DST) + 16384 + ws1) = l;            \
      cvt_split(F2, h, l); *(short8*)((DST) + ws2) = h;                    \
                           *(short8*)((DST) + 16384 + ws2) = l;            \
      cvt_split(F3, h, l); *(short8*)((DST) + ws3) = h;                    \
                           *(short8*)((DST) + 16384 + ws3) = l;            \
    }

    // prologue: B frags for chunk 0, x chunk 0 staged to LDS
    LDB(0, wb) LDB(1, wb) LDB(2, wb) LDB(3, wb)
    LDB(4, wb) LDB(5, wb) LDB(6, wb) LDB(7, wb)
    {
      float8 f0 = *(const float8*)xg;
      float8 f1 = *(const float8*)(xg + 8);
      float8 f2 = *(const float8*)(xg + 16);
      float8 f3 = *(const float8*)(xg + 24);
      STAGE(sm[0], f0, f1, f2, f3)
    }
    asm volatile("s_waitcnt lgkmcnt(0)\n\ts_barrier" ::: "memory");

    for (int i = 0; i < NCH; ++i) {
      // 1) issue next-chunk x loads (consumed at step 3)
      float8 f0, f1, f2, f3;
      if (i + 1 < NCH) {
        const int o = (i + 1) * BK;
        f0 = *(const float8*)(xg + o);
        f1 = *(const float8*)(xg + o + 8);
        f2 = *(const float8*)(xg + o + 16);
        f3 = *(const float8*)(xg + o + 24);
      }
      // 2) compute chunk i; each step reloads its B frag for chunk i+1
      const char* s   = sm[i & 1];
      const char* wbn = wb + (size_t)((i + 1 < NCH) ? i + 1 : i) * (NSTEP * 8192);

#define STEP(K)                                                            \
    {                                                                      \
      const int sa = ((((K) << 2) + t4) ^ axr) << 4;                       \
      short8 ah0 = *(const short8*)(s + ra + sa);                          \
      short8 al0 = *(const short8*)(s + 16384 + ra + sa);                  \
      short8 ah1 = *(const short8*)(s + 8192 + ra + sa);                   \
      short8 al1 = *(const short8*)(s + 24576 + ra + sa);                  \
      acc0 = __builtin_amdgcn_mfma_f32_16x16x32_bf16(ah0, bh##K, acc0, 0, 0, 0); \
      acc0 = __builtin_amdgcn_mfma_f32_16x16x32_bf16(ah0, bl##K, acc0, 0, 0, 0); \
      acc0 = __builtin_amdgcn_mfma_f32_16x16x32_bf16(al0, bh##K, acc0, 0, 0, 0); \
      acc1 = __builtin_amdgcn_mfma_f32_16x16x32_bf16(ah1, bh##K, acc1, 0, 0, 0); \
      acc1 = __builtin_amdgcn_mfma_f32_16x16x32_bf16(ah1, bl##K, acc1, 0, 0, 0); \
      acc1 = __builtin_amdgcn_mfma_f32_16x16x32_bf16(al1, bh##K, acc1, 0, 0, 0); \
      LDB(K, wbn)                                                          \
    }

      STEP(0) STEP(1) STEP(2) STEP(3)
      STEP(4) STEP(5) STEP(6) STEP(7)

      // 3) convert + write next x chunk into the other buffer
      if (i + 1 < NCH) {
        STAGE(sm[(i + 1) & 1], f0, f1, f2, f3)
      }
      // barrier with LDS-drain only: global prefetches stay in flight
      asm volatile("s_waitcnt lgkmcnt(0)\n\ts_barrier" ::: "memory");
    }
#undef STEP
#undef STAGE
#undef LDB
  } else {
    // bf16 fallback (unexercised; register-direct, no d_ws dependency)
    const short* xp0 = (const short*)xv + (size_t)(r0 + lm) * D_DIM + t4 * 8;
    const short* xp1 = xp0 + (size_t)16 * D_DIM;
    const short* wp  = (const short*)wv + (size_t)(wave * 16 + lm) * D_DIM + t4 * 8;
    for (int k = 0; k < D_DIM; k += 32) {
      short8 a0 = *(const short8*)(xp0 + k);
      short8 a1 = *(const short8*)(xp1 + k);
      short8 b0 = *(const short8*)(wp + k);
      acc0 = __builtin_amdgcn_mfma_f32_16x16x32_bf16(a0, b0, acc0, 0, 0, 0);
      acc1 = __builtin_amdgcn_mfma_f32_16x16x32_bf16(a1, b0, acc1, 0, 0, 0);
    }
  }

  // C/D layout (m89-verified): col = lane&15 (expert), row = (lane>>4)*4 + reg
  {
    const int col   = wave * 16 + lm;
    const int rbase = t4 << 2;
#pragma unroll
    for (int r = 0; r < 4; ++r) {
      lg[rbase + r][col]      = acc0[r];
      lg[16 + rbase + r][col] = acc1[r];
    }
  }
  __syncthreads();

  if (tid < BR) {
    const int row = tid;
    float m1 = -3.4e38f, m2 = -3.4e38f;
    int   i1 = 0, i2 = 0;
    for (int e = 0; e < E_DIM; ++e) {
      float be = isbf ? __bfloat162float(((const __hip_bfloat16*)bv)[e])
                      : ((const float*)bv)[e];
      float l = lg[row][e] + be;
      if (l > m1)      { m2 = m1; i2 = i1; m1 = l; i1 = e; }
      else if (l > m2) { m2 = l;  i2 = e; }
    }
    float s = 0.f;
    for (int e = 0; e < E_DIM; ++e) {
      float be = isbf ? __bfloat162float(((const __hip_bfloat16*)bv)[e])
                      : ((const float*)bv)[e];
      s += expf(lg[row][e] + be - m1);
    }
    const int gr = r0 + row;
    // outputs concatenated flat: [N*2 indices][N*2 weights], all as float32
    out[2 * gr]                  = (float)i1;
    out[2 * gr + 1]              = (float)i2;
    out[2 * N_ROWS + 2 * gr]     = 1.0f / s;                 // exp(m1-m1)/s
    out[2 * N_ROWS + 2 * gr + 1] = expf(m2 - m1) / s;
  }
}

extern "C" void kernel_launch(void* const* d_in, const int* in_sizes, int n_in,
                              void* d_out, int out_size, void* d_ws, size_t ws_size,
                              hipStream_t stream) {
  (void)in_sizes; (void)n_in; (void)out_size; (void)ws_size;
  // prep_w writes 1 MB of fragment-ordered split-bf16 W into d_ws;
  // same-stream ordering guarantees completion before router_kernel.
  prep_w<<<dim3(64), dim3(512), 0, stream>>>(d_in[0], d_in[1], d_ws);
  router_kernel<<<dim3(N_ROWS / BR), dim3(256), 0, stream>>>(
      d_in[0], d_in[1], d_in[2], d_ws, (float*)d_out);
}